// Round 1
// baseline (101.047 us; speedup 1.0000x reference)
//
#include <hip/hip_runtime.h>
#include <math.h>

#define NV 12
#define BATCH 4096
#define DIM 128
#define ALPHA_C 0.4f
#define BETA_C 2.0f
#define LAMDA_C 2.0f
#define LDSPAD 132   // 132*4B = 528B rows: 16B-aligned, bank-staggered

__device__ __forceinline__ void acc4(const float4 a, const float4 n, float& s) {
    float dx;
    dx = a.x - n.x; s += dx * dx;
    dx = a.y - n.y; s += dx * dx;
    dx = a.z - n.z; s += dx * dx;
    dx = a.w - n.w; s += dx * dx;
}

// One wave (64 threads) per batch element.
__global__ __launch_bounds__(64) void perb_kernel(
    const float* __restrict__ SV_A, const float* __restrict__ SV_N,
    const float* __restrict__ MV_A, const float* __restrict__ MV_N,
    float4* __restrict__ perb)
{
    const int b    = blockIdx.x;
    const int lane = threadIdx.x;

    __shared__ float As[NV][LDSPAD];
    __shared__ float Ns[NV][LDSPAD];

    // ---- stage SV_A[:,b,:], SV_N[:,b,:] into LDS (coalesced float2) ----
    const int k2 = lane * 2;
    #pragma unroll
    for (int i = 0; i < NV; ++i) {
        const size_t off = ((size_t)(i * BATCH + b)) * DIM + k2;
        const float2 a = *(const float2*)(SV_A + off);
        const float2 n = *(const float2*)(SV_N + off);
        *(float2*)&As[i][k2] = a;
        *(float2*)&Ns[i][k2] = n;
    }
    __syncthreads();

    // ---- 144 pairwise squared distances: 2x2 pair tile per lane ----
    float best_d = 3.4e38f;
    int   best_p = 1 << 20;
    if (lane < 36) {
        const int i2 = lane / 6;
        const int j2 = lane % 6;
        const float* a0p = As[2 * i2];
        const float* a1p = As[2 * i2 + 1];
        const float* n0p = Ns[2 * j2];
        const float* n1p = Ns[2 * j2 + 1];
        float s00 = 0.f, s01 = 0.f, s10 = 0.f, s11 = 0.f;
        #pragma unroll
        for (int k = 0; k < DIM; k += 4) {
            const float4 a0 = *(const float4*)(a0p + k);
            const float4 a1 = *(const float4*)(a1p + k);
            const float4 n0 = *(const float4*)(n0p + k);
            const float4 n1 = *(const float4*)(n1p + k);
            acc4(a0, n0, s00);
            acc4(a0, n1, s01);
            acc4(a1, n0, s10);
            acc4(a1, n1, s11);
        }
        // flat index p = i*12 + j; evaluate in ascending p for argmin tie-break
        const int p00 = (2 * i2) * NV + 2 * j2;
        best_d = s00; best_p = p00;
        if (s01 < best_d) { best_d = s01; best_p = p00 + 1; }
        if (s10 < best_d) { best_d = s10; best_p = p00 + NV; }
        if (s11 < best_d) { best_d = s11; best_p = p00 + NV + 1; }
    }

    // ---- wave argmin reduction (prefer smaller p on ties, JAX semantics) ----
    #pragma unroll
    for (int off = 32; off > 0; off >>= 1) {
        const float od = __shfl_down(best_d, off, 64);
        const int   op = __shfl_down(best_p, off, 64);
        if (od < best_d || (od == best_d && op < best_p)) { best_d = od; best_p = op; }
    }
    best_d = __shfl(best_d, 0, 64);
    best_p = __shfl(best_p, 0, 64);

    const int istar = best_p / NV;
    const int jstar = best_p % NV;

    // ---- three 128-dim norms with all 64 lanes ----
    float sa = 0.f, sc = 0.f, sm = 0.f;
    #pragma unroll
    for (int t = 0; t < 2; ++t) {
        const int k = lane + t * 64;
        const float ma = MV_A[(size_t)b * DIM + k];
        const float mn = MV_N[(size_t)b * DIM + k];
        const float fa = As[istar][k];
        const float fn = Ns[jstar][k];
        float d1;
        d1 = ma - fa; sa += d1 * d1;
        d1 = mn - fn; sc += d1 * d1;
        d1 = ma - mn; sm += d1 * d1;
    }
    #pragma unroll
    for (int off = 32; off > 0; off >>= 1) {
        sa += __shfl_down(sa, off, 64);
        sc += __shfl_down(sc, off, 64);
        sm += __shfl_down(sm, off, 64);
    }

    if (lane == 0) {
        const float mc    = best_d;          // min squared distance
        const float a_cl  = sqrtf(sa);
        const float c_in  = sqrtf(sc);
        const float mv_in = sqrtf(sm);
        const float loss  = LAMDA_C * (fmaxf(BETA_C - mc, 0.f) + fmaxf(BETA_C - mv_in, 0.f))
                          + fmaxf(a_cl - ALPHA_C, 0.f) + fmaxf(c_in - ALPHA_C, 0.f);
        float4 o;
        o.x = loss;
        o.y = (loss != 0.f) ? 1.f : 0.f;
        o.z = sqrtf(mc);                      // sqrt(mc_inter)
        o.w = 0.5f * (sqrtf(a_cl) + sqrtf(c_in));
        perb[b] = o;
    }
}

// Single-block deterministic final reduction over 4096 per-b records.
__global__ __launch_bounds__(256) void final_kernel(
    const float4* __restrict__ perb, float* __restrict__ out)
{
    const int t = threadIdx.x;
    float sl = 0.f, sn = 0.f, ss = 0.f, sh = 0.f, mnv = 3.4e38f;
    for (int idx = t; idx < BATCH; idx += 256) {
        const float4 v = perb[idx];
        sl += v.x; sn += v.y; ss += v.z; sh += v.w;
        mnv = fminf(mnv, v.z);
    }
    #pragma unroll
    for (int off = 32; off > 0; off >>= 1) {
        sl += __shfl_down(sl, off, 64);
        sn += __shfl_down(sn, off, 64);
        ss += __shfl_down(ss, off, 64);
        sh += __shfl_down(sh, off, 64);
        mnv = fminf(mnv, __shfl_down(mnv, off, 64));
    }
    __shared__ float r[4][5];
    const int w = t >> 6;
    if ((t & 63) == 0) {
        r[w][0] = sl; r[w][1] = sn; r[w][2] = ss; r[w][3] = sh; r[w][4] = mnv;
    }
    __syncthreads();
    if (t == 0) {
        #pragma unroll
        for (int i = 1; i < 4; ++i) {
            sl += r[i][0]; sn += r[i][1]; ss += r[i][2]; sh += r[i][3];
            mnv = fminf(mnv, r[i][4]);
        }
        const float inv = 1.0f / (float)BATCH;
        out[0] = sl * inv;   // avg_loss
        out[1] = sn;         // count_nonzero
        out[2] = ss * inv;   // mean(sqrt(mc_inter))
        out[3] = sh * inv;   // 0.5*(mean(sqrt(a_clstr)) + mean(sqrt(c_intra)))
        out[4] = mnv;        // min(sqrt(mc_inter))
    }
}

extern "C" void kernel_launch(void* const* d_in, const int* in_sizes, int n_in,
                              void* d_out, int out_size, void* d_ws, size_t ws_size,
                              hipStream_t stream) {
    const float* SV_A = (const float*)d_in[0];
    const float* SV_N = (const float*)d_in[1];
    const float* MV_A = (const float*)d_in[2];
    const float* MV_N = (const float*)d_in[3];
    float* out = (float*)d_out;
    float4* perb = (float4*)d_ws;   // 4096 * 16B = 64 KiB

    perb_kernel<<<BATCH, 64, 0, stream>>>(SV_A, SV_N, MV_A, MV_N, perb);
    final_kernel<<<1, 256, 0, stream>>>(perb, out);
}

// Round 2
// 99.754 us; speedup vs baseline: 1.0130x; 1.0130x over previous
//
#include <hip/hip_runtime.h>
#include <math.h>

#define NV 12
#define BATCH 4096
#define DIM 128
#define ALPHA_C 0.4f
#define BETA_C 2.0f
#define LAMDA_C 2.0f
#define LDSPAD 132   // 132*4B = 528B rows: 16B-aligned, bank-staggered (2-way max)
#define BPB 4        // batch elements per block (one wave each)

__device__ __forceinline__ void acc4(const float4 a, const float4 n, float& s) {
    float dx;
    dx = a.x - n.x; s += dx * dx;
    dx = a.y - n.y; s += dx * dx;
    dx = a.z - n.z; s += dx * dx;
    dx = a.w - n.w; s += dx * dx;
}

// 256 threads = 4 waves; each wave owns one batch element. No __syncthreads():
// every wave reads only the LDS tiles it wrote itself (lgkmcnt handles RAW).
__global__ __launch_bounds__(256) void perb_kernel(
    const float* __restrict__ SV_A, const float* __restrict__ SV_N,
    const float* __restrict__ MV_A, const float* __restrict__ MV_N,
    float4* __restrict__ perb)
{
    const int wave = threadIdx.x >> 6;
    const int lane = threadIdx.x & 63;
    const int b    = blockIdx.x * BPB + wave;

    __shared__ float As[BPB][NV][LDSPAD];
    __shared__ float Ns[BPB][NV][LDSPAD];

    // ---- stage SV_A[:,b,:], SV_N[:,b,:]: float4, 2 rows per instruction ----
    {
        const int half = lane >> 5;            // 0: even row, 1: odd row
        const int c    = (lane & 31) * 4;      // column (dwords)
        #pragma unroll
        for (int r = 0; r < NV / 2; ++r) {
            const int i = 2 * r + half;
            const size_t off = ((size_t)(i * BATCH + b)) * DIM + c;
            *(float4*)&As[wave][i][c] = *(const float4*)(SV_A + off);
            *(float4*)&Ns[wave][i][c] = *(const float4*)(SV_N + off);
        }
    }

    // ---- 144 pairwise squared distances: 2x2 pair tile, lanes 0..35 ----
    float best_d = 3.4e38f;
    int   best_p = 1 << 20;
    if (lane < 36) {
        const int i2 = lane / 6;
        const int j2 = lane % 6;
        const float* a0p = As[wave][2 * i2];
        const float* a1p = As[wave][2 * i2 + 1];
        const float* n0p = Ns[wave][2 * j2];
        const float* n1p = Ns[wave][2 * j2 + 1];
        float s00 = 0.f, s01 = 0.f, s10 = 0.f, s11 = 0.f;
        #pragma unroll
        for (int k = 0; k < DIM; k += 4) {
            const float4 a0 = *(const float4*)(a0p + k);
            const float4 a1 = *(const float4*)(a1p + k);
            const float4 n0 = *(const float4*)(n0p + k);
            const float4 n1 = *(const float4*)(n1p + k);
            acc4(a0, n0, s00);
            acc4(a0, n1, s01);
            acc4(a1, n0, s10);
            acc4(a1, n1, s11);
        }
        // flat p = i*12 + j; ascending-p evaluation preserves argmin tie-break
        const int p00 = (2 * i2) * NV + 2 * j2;
        best_d = s00; best_p = p00;
        if (s01 < best_d) { best_d = s01; best_p = p00 + 1; }
        if (s10 < best_d) { best_d = s10; best_p = p00 + NV; }
        if (s11 < best_d) { best_d = s11; best_p = p00 + NV + 1; }
    }

    // ---- wave argmin (smaller flat index wins ties — JAX semantics) ----
    #pragma unroll
    for (int off = 32; off > 0; off >>= 1) {
        const float od = __shfl_down(best_d, off, 64);
        const int   op = __shfl_down(best_p, off, 64);
        if (od < best_d || (od == best_d && op < best_p)) { best_d = od; best_p = op; }
    }
    best_d = __shfl(best_d, 0, 64);
    best_p = __shfl(best_p, 0, 64);

    const int istar = best_p / NV;
    const int jstar = best_p % NV;

    // ---- three 128-dim norms with all 64 lanes ----
    float sa = 0.f, sc = 0.f, sm = 0.f;
    #pragma unroll
    for (int t = 0; t < 2; ++t) {
        const int k = lane + t * 64;
        const float ma = MV_A[(size_t)b * DIM + k];
        const float mn = MV_N[(size_t)b * DIM + k];
        const float fa = As[wave][istar][k];
        const float fn = Ns[wave][jstar][k];
        float d1;
        d1 = ma - fa; sa += d1 * d1;
        d1 = mn - fn; sc += d1 * d1;
        d1 = ma - mn; sm += d1 * d1;
    }
    #pragma unroll
    for (int off = 32; off > 0; off >>= 1) {
        sa += __shfl_down(sa, off, 64);
        sc += __shfl_down(sc, off, 64);
        sm += __shfl_down(sm, off, 64);
    }

    if (lane == 0) {
        const float mc    = best_d;
        const float a_cl  = sqrtf(sa);
        const float c_in  = sqrtf(sc);
        const float mv_in = sqrtf(sm);
        const float loss  = LAMDA_C * (fmaxf(BETA_C - mc, 0.f) + fmaxf(BETA_C - mv_in, 0.f))
                          + fmaxf(a_cl - ALPHA_C, 0.f) + fmaxf(c_in - ALPHA_C, 0.f);
        float4 o;
        o.x = loss;
        o.y = (loss != 0.f) ? 1.f : 0.f;
        o.z = sqrtf(mc);
        o.w = 0.5f * (sqrtf(a_cl) + sqrtf(c_in));
        perb[b] = o;
    }
}

// Single-block deterministic final reduction: 1024 threads, 4 records each.
__global__ __launch_bounds__(1024) void final_kernel(
    const float4* __restrict__ perb, float* __restrict__ out)
{
    const int t = threadIdx.x;
    float sl = 0.f, sn = 0.f, ss = 0.f, sh = 0.f, mnv = 3.4e38f;
    #pragma unroll
    for (int u = 0; u < BATCH / 1024; ++u) {
        const float4 v = perb[t + u * 1024];
        sl += v.x; sn += v.y; ss += v.z; sh += v.w;
        mnv = fminf(mnv, v.z);
    }
    #pragma unroll
    for (int off = 32; off > 0; off >>= 1) {
        sl += __shfl_down(sl, off, 64);
        sn += __shfl_down(sn, off, 64);
        ss += __shfl_down(ss, off, 64);
        sh += __shfl_down(sh, off, 64);
        mnv = fminf(mnv, __shfl_down(mnv, off, 64));
    }
    __shared__ float r[16][5];
    const int w = t >> 6;
    if ((t & 63) == 0) {
        r[w][0] = sl; r[w][1] = sn; r[w][2] = ss; r[w][3] = sh; r[w][4] = mnv;
    }
    __syncthreads();
    if (t == 0) {
        #pragma unroll
        for (int i = 1; i < 16; ++i) {
            sl += r[i][0]; sn += r[i][1]; ss += r[i][2]; sh += r[i][3];
            mnv = fminf(mnv, r[i][4]);
        }
        const float inv = 1.0f / (float)BATCH;
        out[0] = sl * inv;   // avg_loss
        out[1] = sn;         // count_nonzero
        out[2] = ss * inv;   // mean(sqrt(mc_inter))
        out[3] = sh * inv;   // 0.5*(mean sqrt(a_clstr) + mean sqrt(c_intra))
        out[4] = mnv;        // min(sqrt(mc_inter))
    }
}

extern "C" void kernel_launch(void* const* d_in, const int* in_sizes, int n_in,
                              void* d_out, int out_size, void* d_ws, size_t ws_size,
                              hipStream_t stream) {
    const float* SV_A = (const float*)d_in[0];
    const float* SV_N = (const float*)d_in[1];
    const float* MV_A = (const float*)d_in[2];
    const float* MV_N = (const float*)d_in[3];
    float* out = (float*)d_out;
    float4* perb = (float4*)d_ws;   // 4096 * 16B = 64 KiB

    perb_kernel<<<BATCH / BPB, 256, 0, stream>>>(SV_A, SV_N, MV_A, MV_N, perb);
    final_kernel<<<1, 1024, 0, stream>>>(perb, out);
}

// Round 3
// 99.529 us; speedup vs baseline: 1.0152x; 1.0023x over previous
//
#include <hip/hip_runtime.h>
#include <math.h>

#define NV 12
#define BATCH 4096
#define DIM 128
#define ALPHA_C 0.4f
#define BETA_C 2.0f
#define LAMDA_C 2.0f
#define LDSPAD 132   // 528B rows: 16B-aligned, max 2-way bank alias (free)
#define BPB 4        // batch elements per block, one wave each

// 256 threads = 4 waves; each wave owns one batch element. No __syncthreads():
// every wave reads only LDS it wrote itself (compiler lgkmcnt handles RAW).
__global__ __launch_bounds__(256) void perb_kernel(
    const float* __restrict__ SV_A, const float* __restrict__ SV_N,
    const float* __restrict__ MV_A, const float* __restrict__ MV_N,
    float4* __restrict__ perb)
{
    const int wave = threadIdx.x >> 6;
    const int lane = threadIdx.x & 63;
    const int b    = blockIdx.x * BPB + wave;

    __shared__ float As[BPB][NV][LDSPAD];
    __shared__ float Ns[BPB][NV][LDSPAD];
    __shared__ float normsA[BPB][NV];
    __shared__ float normsN[BPB][NV];

    // ---- prefetch MV rows (latency hidden under distance phase) ----
    const size_t mvoff = (size_t)b * DIM + lane;
    const float ma0 = MV_A[mvoff];
    const float ma1 = MV_A[mvoff + 64];
    const float mn0 = MV_N[mvoff];
    const float mn1 = MV_N[mvoff + 64];

    // ---- stage SV_A[:,b,:], SV_N[:,b,:]: float4, 2 rows per instruction ----
    {
        const int half = lane >> 5;            // 0: even rows, 1: odd rows
        const int c    = (lane & 31) * 4;
        #pragma unroll
        for (int r = 0; r < NV / 2; ++r) {
            const int i = 2 * r + half;
            const size_t off = ((size_t)(i * BATCH + b)) * DIM + c;
            *(float4*)&As[wave][i][c] = *(const float4*)(SV_A + off);
            *(float4*)&Ns[wave][i][c] = *(const float4*)(SV_N + off);
        }
    }

    // ---- row squared-norms: lanes 0..23, one row each ----
    if (lane < 2 * NV) {
        const int arr = lane >= NV;
        const int row = arr ? (lane - NV) : lane;
        const float* p = arr ? Ns[wave][row] : As[wave][row];
        float nrm = 0.f;
        #pragma unroll
        for (int k = 0; k < DIM; k += 4) {
            const float4 v = *(const float4*)(p + k);
            nrm += v.x * v.x + v.y * v.y + v.z * v.z + v.w * v.w;
        }
        if (arr) normsN[wave][row] = nrm;
        else     normsA[wave][row] = nrm;
    }

    // ---- 144 pairwise d via dots: 2x2 pair tile, lanes 0..35 ----
    float best_d = 3.4e38f;
    int   best_p = 1 << 20;
    if (lane < 36) {
        const int i2 = lane / 6;
        const int j2 = lane % 6;
        const float* a0p = As[wave][2 * i2];
        const float* a1p = As[wave][2 * i2 + 1];
        const float* n0p = Ns[wave][2 * j2];
        const float* n1p = Ns[wave][2 * j2 + 1];
        float s00 = 0.f, s01 = 0.f, s10 = 0.f, s11 = 0.f;
        #pragma unroll
        for (int k = 0; k < DIM; k += 4) {
            const float4 a0 = *(const float4*)(a0p + k);
            const float4 a1 = *(const float4*)(a1p + k);
            const float4 n0 = *(const float4*)(n0p + k);
            const float4 n1 = *(const float4*)(n1p + k);
            s00 += a0.x * n0.x + a0.y * n0.y + a0.z * n0.z + a0.w * n0.w;
            s01 += a0.x * n1.x + a0.y * n1.y + a0.z * n1.z + a0.w * n1.w;
            s10 += a1.x * n0.x + a1.y * n0.y + a1.z * n0.z + a1.w * n0.w;
            s11 += a1.x * n1.x + a1.y * n1.y + a1.z * n1.z + a1.w * n1.w;
        }
        const float na0 = normsA[wave][2 * i2];
        const float na1 = normsA[wave][2 * i2 + 1];
        const float nn0 = normsN[wave][2 * j2];
        const float nn1 = normsN[wave][2 * j2 + 1];
        const float d00 = na0 + nn0 - 2.f * s00;
        const float d01 = na0 + nn1 - 2.f * s01;
        const float d10 = na1 + nn0 - 2.f * s10;
        const float d11 = na1 + nn1 - 2.f * s11;
        // flat p = i*12 + j; ascending-p evaluation preserves argmin tie-break
        const int p00 = (2 * i2) * NV + 2 * j2;
        best_d = d00; best_p = p00;
        if (d01 < best_d) { best_d = d01; best_p = p00 + 1; }
        if (d10 < best_d) { best_d = d10; best_p = p00 + NV; }
        if (d11 < best_d) { best_d = d11; best_p = p00 + NV + 1; }
    }

    // ---- wave argmin (smaller flat index wins ties — JAX semantics) ----
    #pragma unroll
    for (int off = 32; off > 0; off >>= 1) {
        const float od = __shfl_down(best_d, off, 64);
        const int   op = __shfl_down(best_p, off, 64);
        if (od < best_d || (od == best_d && op < best_p)) { best_d = od; best_p = op; }
    }
    best_d = __shfl(best_d, 0, 64);
    best_p = __shfl(best_p, 0, 64);

    const int istar = best_p / NV;
    const int jstar = best_p % NV;

    // ---- three 128-dim norms with all 64 lanes (MV already in regs) ----
    float sa, sc, sm;
    {
        const float fa0 = As[wave][istar][lane];
        const float fa1 = As[wave][istar][lane + 64];
        const float fn0 = Ns[wave][jstar][lane];
        const float fn1 = Ns[wave][jstar][lane + 64];
        float d1;
        d1 = ma0 - fa0; sa  = d1 * d1;
        d1 = ma1 - fa1; sa += d1 * d1;
        d1 = mn0 - fn0; sc  = d1 * d1;
        d1 = mn1 - fn1; sc += d1 * d1;
        d1 = ma0 - mn0; sm  = d1 * d1;
        d1 = ma1 - mn1; sm += d1 * d1;
    }
    #pragma unroll
    for (int off = 32; off > 0; off >>= 1) {
        sa += __shfl_down(sa, off, 64);
        sc += __shfl_down(sc, off, 64);
        sm += __shfl_down(sm, off, 64);
    }

    if (lane == 0) {
        const float mc    = fmaxf(best_d, 0.f);
        const float a_cl  = sqrtf(sa);
        const float c_in  = sqrtf(sc);
        const float mv_in = sqrtf(sm);
        const float loss  = LAMDA_C * (fmaxf(BETA_C - mc, 0.f) + fmaxf(BETA_C - mv_in, 0.f))
                          + fmaxf(a_cl - ALPHA_C, 0.f) + fmaxf(c_in - ALPHA_C, 0.f);
        float4 o;
        o.x = loss;
        o.y = (loss != 0.f) ? 1.f : 0.f;
        o.z = sqrtf(mc);
        o.w = 0.5f * (sqrtf(a_cl) + sqrtf(c_in));
        perb[b] = o;
    }
}

// Single-block deterministic final reduction: 1024 threads, 4 records each.
__global__ __launch_bounds__(1024) void final_kernel(
    const float4* __restrict__ perb, float* __restrict__ out)
{
    const int t = threadIdx.x;
    float sl = 0.f, sn = 0.f, ss = 0.f, sh = 0.f, mnv = 3.4e38f;
    #pragma unroll
    for (int u = 0; u < BATCH / 1024; ++u) {
        const float4 v = perb[t + u * 1024];
        sl += v.x; sn += v.y; ss += v.z; sh += v.w;
        mnv = fminf(mnv, v.z);
    }
    #pragma unroll
    for (int off = 32; off > 0; off >>= 1) {
        sl += __shfl_down(sl, off, 64);
        sn += __shfl_down(sn, off, 64);
        ss += __shfl_down(ss, off, 64);
        sh += __shfl_down(sh, off, 64);
        mnv = fminf(mnv, __shfl_down(mnv, off, 64));
    }
    __shared__ float r[16][5];
    const int w = t >> 6;
    if ((t & 63) == 0) {
        r[w][0] = sl; r[w][1] = sn; r[w][2] = ss; r[w][3] = sh; r[w][4] = mnv;
    }
    __syncthreads();
    if (t == 0) {
        #pragma unroll
        for (int i = 1; i < 16; ++i) {
            sl += r[i][0]; sn += r[i][1]; ss += r[i][2]; sh += r[i][3];
            mnv = fminf(mnv, r[i][4]);
        }
        const float inv = 1.0f / (float)BATCH;
        out[0] = sl * inv;   // avg_loss
        out[1] = sn;         // count_nonzero
        out[2] = ss * inv;   // mean(sqrt(mc_inter))
        out[3] = sh * inv;   // 0.5*(mean sqrt(a_clstr) + mean sqrt(c_intra))
        out[4] = mnv;        // min(sqrt(mc_inter))
    }
}

extern "C" void kernel_launch(void* const* d_in, const int* in_sizes, int n_in,
                              void* d_out, int out_size, void* d_ws, size_t ws_size,
                              hipStream_t stream) {
    const float* SV_A = (const float*)d_in[0];
    const float* SV_N = (const float*)d_in[1];
    const float* MV_A = (const float*)d_in[2];
    const float* MV_N = (const float*)d_in[3];
    float* out = (float*)d_out;
    float4* perb = (float4*)d_ws;   // 4096 * 16B = 64 KiB

    perb_kernel<<<BATCH / BPB, 256, 0, stream>>>(SV_A, SV_N, MV_A, MV_N, perb);
    final_kernel<<<1, 1024, 0, stream>>>(perb, out);
}